// Round 5
// baseline (148.513 us; speedup 1.0000x reference)
//
#include <hip/hip_runtime.h>

// GCN layer: out = ReLU(x @ U^T + segment_sum(x[src], dst) @ V^T)
// x: [50000, 64] f32, src/dst: [1M] i32, U/V: [64, 64] f32, out: [50000, 64] f32
//
// Round 5:
//  - gather reads an fp16 copy of x (half the random-row bytes; working set
//    6.4 MB vs 12.8 MB against 4 MB/XCD L2). Accumulate f32; x@U^T stays f32.
//  - scan_small merged into scan_apply (one fewer dependent launch).

constexpr int N_NODES = 50000;
constexpr int N_EDGES = 1000000;
constexpr int D = 64;

constexpr int SCAN_ELEMS_PER_BLOCK = 512;
constexpr int SCAN_BLOCKS = (N_NODES + SCAN_ELEMS_PER_BLOCK - 1)
                            / SCAN_ELEMS_PER_BLOCK;  // 98

// ---------------------------------------------------------------------------
// x (f32) -> xh (fp16). 3.2M elems, 4/thread, exact grid.
// ---------------------------------------------------------------------------
__global__ __launch_bounds__(256) void cvt_fp16_kernel(
    const float* __restrict__ x, _Float16* __restrict__ xh)
{
    const int i = (blockIdx.x * 256 + threadIdx.x) * 4;
    const float4 v = *reinterpret_cast<const float4*>(x + i);
    union { _Float16 h[4]; unsigned long long u; } p;
    p.h[0] = (_Float16)v.x;
    p.h[1] = (_Float16)v.y;
    p.h[2] = (_Float16)v.z;
    p.h[3] = (_Float16)v.w;
    *reinterpret_cast<unsigned long long*>(xh + i) = p.u;
}

// ---------------------------------------------------------------------------
// CSR step 1: degree histogram + per-edge rank pack. packed = (rank<<16)|src.
// ---------------------------------------------------------------------------
__global__ __launch_bounds__(256) void degree_pack_kernel(
    const int* __restrict__ src, const int* __restrict__ dst,
    int* __restrict__ deg, int* __restrict__ packed)
{
    const int q = blockIdx.x * 256 + threadIdx.x;
    const int e = q * 4;
    if (e + 3 < N_EDGES) {
        const int4 d4 = *reinterpret_cast<const int4*>(dst + e);
        const int4 s4 = *reinterpret_cast<const int4*>(src + e);
        int4 p4;
        p4.x = (atomicAdd(&deg[d4.x], 1) << 16) | s4.x;
        p4.y = (atomicAdd(&deg[d4.y], 1) << 16) | s4.y;
        p4.z = (atomicAdd(&deg[d4.z], 1) << 16) | s4.z;
        p4.w = (atomicAdd(&deg[d4.w], 1) << 16) | s4.w;
        *reinterpret_cast<int4*>(packed + e) = p4;
    } else {
        for (int i = e; i < N_EDGES; ++i)
            packed[i] = (atomicAdd(&deg[dst[i]], 1) << 16) | src[i];
    }
}

// Plain degree histogram (mid fallback path).
__global__ __launch_bounds__(256) void degree_kernel(
    const int* __restrict__ dst, int* __restrict__ deg)
{
    const int q = blockIdx.x * 256 + threadIdx.x;
    const int e = q * 4;
    if (e + 3 < N_EDGES) {
        const int4 d4 = *reinterpret_cast<const int4*>(dst + e);
        atomicAdd(&deg[d4.x], 1);
        atomicAdd(&deg[d4.y], 1);
        atomicAdd(&deg[d4.z], 1);
        atomicAdd(&deg[d4.w], 1);
    } else {
        for (int i = e; i < N_EDGES; ++i) atomicAdd(&deg[dst[i]], 1);
    }
}

// ---------------------------------------------------------------------------
// CSR step 2a: per-block partial sums of deg (512 elems/block).
// ---------------------------------------------------------------------------
__global__ __launch_bounds__(256) void scan_partial_kernel(
    const int* __restrict__ deg, int* __restrict__ block_sums)
{
    __shared__ int red[256];
    const int t = threadIdx.x;
    const int idx = blockIdx.x * SCAN_ELEMS_PER_BLOCK + t * 2;
    int s = 0;
    if (idx < N_NODES)     s += deg[idx];
    if (idx + 1 < N_NODES) s += deg[idx + 1];
    red[t] = s;
    __syncthreads();
    for (int off = 128; off > 0; off >>= 1) {
        if (t < off) red[t] += red[t + off];
        __syncthreads();
    }
    if (t == 0) block_sums[blockIdx.x] = red[0];
}

// ---------------------------------------------------------------------------
// CSR step 2b (merged): every block scans the 98 block sums in LDS, takes its
// exclusive offset, then does its local 512-elem scan; writes row_start and
// inits cursor (aliases deg). Block 0 also writes row_start[N_NODES].
// ---------------------------------------------------------------------------
__global__ __launch_bounds__(256) void scan_apply_kernel(
    int* deg_cursor, const int* __restrict__ block_sums,
    int* __restrict__ row_start)
{
    __shared__ int sbuf[256];
    __shared__ int bsum[128];
    const int t = threadIdx.x;

    if (t < 128) bsum[t] = (t < SCAN_BLOCKS) ? block_sums[t] : 0;
    __syncthreads();
    for (int off = 1; off < 128; off <<= 1) {
        int u = 0;
        if (t < 128 && t >= off) u = bsum[t - off];
        __syncthreads();
        if (t < 128) bsum[t] += u;
        __syncthreads();
    }
    const int blk_off = (blockIdx.x == 0) ? 0 : bsum[blockIdx.x - 1];
    if (blockIdx.x == 0 && t == 0) row_start[N_NODES] = bsum[127];

    const int idx = blockIdx.x * SCAN_ELEMS_PER_BLOCK + t * 2;
    const int d0 = (idx < N_NODES)     ? deg_cursor[idx]     : 0;
    const int d1 = (idx + 1 < N_NODES) ? deg_cursor[idx + 1] : 0;
    const int ts = d0 + d1;
    sbuf[t] = ts;
    __syncthreads();
    for (int off = 1; off < 256; off <<= 1) {
        const int u = (t >= off) ? sbuf[t - off] : 0;
        __syncthreads();
        sbuf[t] += u;
        __syncthreads();
    }
    const int pre = sbuf[t] - ts + blk_off;
    if (idx < N_NODES)     { row_start[idx] = pre;          deg_cursor[idx] = pre; }
    if (idx + 1 < N_NODES) { row_start[idx + 1] = pre + d0; deg_cursor[idx + 1] = pre + d0; }
}

// ---------------------------------------------------------------------------
// CSR step 3 (fast path): atomic-free bucket scatter via precomputed ranks.
// ---------------------------------------------------------------------------
__global__ __launch_bounds__(256) void fill_pos_kernel(
    const int* __restrict__ dst, const int* __restrict__ packed,
    const int* __restrict__ row_start, int* __restrict__ edge_src)
{
    const int q = blockIdx.x * 256 + threadIdx.x;
    const int e = q * 4;
    if (e + 3 < N_EDGES) {
        const int4 d4 = *reinterpret_cast<const int4*>(dst + e);
        const int4 p4 = *reinterpret_cast<const int4*>(packed + e);
        edge_src[row_start[d4.x] + (p4.x >> 16)] = p4.x & 0xFFFF;
        edge_src[row_start[d4.y] + (p4.y >> 16)] = p4.y & 0xFFFF;
        edge_src[row_start[d4.z] + (p4.z >> 16)] = p4.z & 0xFFFF;
        edge_src[row_start[d4.w] + (p4.w >> 16)] = p4.w & 0xFFFF;
    } else {
        for (int i = e; i < N_EDGES; ++i) {
            const int p = packed[i];
            edge_src[row_start[dst[i]] + (p >> 16)] = p & 0xFFFF;
        }
    }
}

// CSR step 3 (mid fallback): atomic-return bucket fill.
__global__ __launch_bounds__(256) void fill_kernel(
    const int* __restrict__ src, const int* __restrict__ dst,
    int* cursor, int* __restrict__ edge_src)
{
    const int q = blockIdx.x * 256 + threadIdx.x;
    const int e = q * 4;
    if (e + 3 < N_EDGES) {
        const int4 d4 = *reinterpret_cast<const int4*>(dst + e);
        const int4 s4 = *reinterpret_cast<const int4*>(src + e);
        edge_src[atomicAdd(&cursor[d4.x], 1)] = s4.x;
        edge_src[atomicAdd(&cursor[d4.y], 1)] = s4.y;
        edge_src[atomicAdd(&cursor[d4.z], 1)] = s4.z;
        edge_src[atomicAdd(&cursor[d4.w], 1)] = s4.w;
    } else {
        for (int i = e; i < N_EDGES; ++i)
            edge_src[atomicAdd(&cursor[dst[i]], 1)] = src[i];
    }
}

// ---------------------------------------------------------------------------
// Fused gather (fp16 rows) + dual-GEMM + ReLU. 512 thr = 8 waves share Ut/Vt;
// one wave per node, lane = output feature.
// ---------------------------------------------------------------------------
__global__ __launch_bounds__(512, 8) void csr_gather_gemm_f16_kernel(
    const float* __restrict__ x, const _Float16* __restrict__ xh,
    const int* __restrict__ row_start, const int* __restrict__ edge_src,
    const float* __restrict__ U, const float* __restrict__ V,
    float* __restrict__ out)
{
    __shared__ float Ut[D][D + 1];
    __shared__ float Vt[D][D + 1];
    __shared__ float rows[8][2][D];  // [wave][x|agg][k]

    const int t = threadIdx.x, o = t & 63, w = t >> 6;

    for (int i = t; i < D * D; i += 512) {
        const int oo = i >> 6, kk = i & 63;
        Ut[kk][oo] = U[i];
        Vt[kk][oo] = V[i];
    }
    __syncthreads();

    const int n = blockIdx.x * 8 + w;   // grid is exactly N_NODES/8
    const int rowoff = n * D + o;

    rows[w][0][o] = x[rowoff];

    const int beg = row_start[n];
    const int end = row_start[n + 1];
    float acc = 0.f;
    int i = beg;
    for (; i + 4 <= end; i += 4) {
        const int s0 = edge_src[i + 0], s1 = edge_src[i + 1];
        const int s2 = edge_src[i + 2], s3 = edge_src[i + 3];
        acc += (float)xh[s0 * D + o];
        acc += (float)xh[s1 * D + o];
        acc += (float)xh[s2 * D + o];
        acc += (float)xh[s3 * D + o];
    }
    for (; i < end; ++i) acc += (float)xh[edge_src[i] * D + o];
    rows[w][1][o] = acc;
    // wave-private LDS rows: no block barrier needed.

    float sum = 0.f;
    #pragma unroll
    for (int k4 = 0; k4 < D / 4; ++k4) {
        const int k = k4 * 4;
        const float4 xq = *reinterpret_cast<const float4*>(&rows[w][0][k]);
        const float4 aq = *reinterpret_cast<const float4*>(&rows[w][1][k]);
        sum += xq.x * Ut[k + 0][o] + aq.x * Vt[k + 0][o];
        sum += xq.y * Ut[k + 1][o] + aq.y * Vt[k + 1][o];
        sum += xq.z * Ut[k + 2][o] + aq.z * Vt[k + 2][o];
        sum += xq.w * Ut[k + 3][o] + aq.w * Vt[k + 3][o];
    }
    out[rowoff] = fmaxf(sum, 0.f);
}

// f32-gather variant (big/mid fallback, no xh space).
__global__ __launch_bounds__(512, 8) void csr_gather_gemm_kernel(
    const float* __restrict__ x, const int* __restrict__ row_start,
    const int* __restrict__ edge_src,
    const float* __restrict__ U, const float* __restrict__ V,
    float* __restrict__ out)
{
    __shared__ float Ut[D][D + 1];
    __shared__ float Vt[D][D + 1];
    __shared__ float rows[8][2][D];

    const int t = threadIdx.x, o = t & 63, w = t >> 6;

    for (int i = t; i < D * D; i += 512) {
        const int oo = i >> 6, kk = i & 63;
        Ut[kk][oo] = U[i];
        Vt[kk][oo] = V[i];
    }
    __syncthreads();

    const int n = blockIdx.x * 8 + w;
    const int rowoff = n * D + o;

    rows[w][0][o] = x[rowoff];

    const int beg = row_start[n];
    const int end = row_start[n + 1];
    float acc = 0.f;
    int i = beg;
    for (; i + 4 <= end; i += 4) {
        const int s0 = edge_src[i + 0], s1 = edge_src[i + 1];
        const int s2 = edge_src[i + 2], s3 = edge_src[i + 3];
        acc += x[s0 * D + o];
        acc += x[s1 * D + o];
        acc += x[s2 * D + o];
        acc += x[s3 * D + o];
    }
    for (; i < end; ++i) acc += x[edge_src[i] * D + o];
    rows[w][1][o] = acc;

    float sum = 0.f;
    #pragma unroll
    for (int k4 = 0; k4 < D / 4; ++k4) {
        const int k = k4 * 4;
        const float4 xq = *reinterpret_cast<const float4*>(&rows[w][0][k]);
        const float4 aq = *reinterpret_cast<const float4*>(&rows[w][1][k]);
        sum += xq.x * Ut[k + 0][o] + aq.x * Vt[k + 0][o];
        sum += xq.y * Ut[k + 1][o] + aq.y * Vt[k + 1][o];
        sum += xq.z * Ut[k + 2][o] + aq.z * Vt[k + 2][o];
        sum += xq.w * Ut[k + 3][o] + aq.w * Vt[k + 3][o];
    }
    out[rowoff] = fmaxf(sum, 0.f);
}

// ---------------------------------------------------------------------------
// Last-resort fallback: atomic scatter + separate GEMM.
// ---------------------------------------------------------------------------
__global__ __launch_bounds__(256) void scatter_add_kernel(
    const float* __restrict__ x, const int* __restrict__ src,
    const int* __restrict__ dst, float* agg)
{
    const int tid = blockIdx.x * 256 + threadIdx.x;
    const int e = tid >> 4;
    const int qq = (tid & 15) << 2;
    const int s = src[e];
    const int d = dst[e];
    const float4 v = *reinterpret_cast<const float4*>(x + s * D + qq);
    float* a = agg + d * D + qq;
    unsafeAtomicAdd(a + 0, v.x);
    unsafeAtomicAdd(a + 1, v.y);
    unsafeAtomicAdd(a + 2, v.z);
    unsafeAtomicAdd(a + 3, v.w);
}

__global__ __launch_bounds__(256) void gemm_relu_kernel(
    const float* __restrict__ x, const float* agg,
    const float* __restrict__ U, const float* __restrict__ V,
    float* out)
{
    __shared__ float Ut[D][D + 1];
    __shared__ float Vt[D][D + 1];
    __shared__ float xs[4][D][4];
    __shared__ float as[4][D][4];

    const int t = threadIdx.x;
    const int o = t & 63;
    const int w = t >> 6;

    for (int i = t; i < D * D; i += 256) {
        const int oo = i >> 6, kk = i & 63;
        Ut[kk][oo] = U[i];
        Vt[kk][oo] = V[i];
    }
    __syncthreads();

    const int nb = blockIdx.x * 16 + w * 4;
    #pragma unroll
    for (int j = 0; j < 4; ++j) {
        const int n = nb + j;
        xs[w][o][j] = x[n * D + o];
        as[w][o][j] = agg[n * D + o];
    }

    float acc0 = 0.f, acc1 = 0.f, acc2 = 0.f, acc3 = 0.f;
    #pragma unroll 16
    for (int k = 0; k < D; ++k) {
        const float u = Ut[k][o];
        const float v = Vt[k][o];
        const float4 xv = *reinterpret_cast<const float4*>(&xs[w][k][0]);
        const float4 av = *reinterpret_cast<const float4*>(&as[w][k][0]);
        acc0 += u * xv.x + v * av.x;
        acc1 += u * xv.y + v * av.y;
        acc2 += u * xv.z + v * av.z;
        acc3 += u * xv.w + v * av.w;
    }

    out[(nb + 0) * D + o] = fmaxf(acc0, 0.f);
    out[(nb + 1) * D + o] = fmaxf(acc1, 0.f);
    out[(nb + 2) * D + o] = fmaxf(acc2, 0.f);
    out[(nb + 3) * D + o] = fmaxf(acc3, 0.f);
}

extern "C" void kernel_launch(void* const* d_in, const int* in_sizes, int n_in,
                              void* d_out, int out_size, void* d_ws, size_t ws_size,
                              hipStream_t stream) {
    const float* x   = (const float*)d_in[0];
    const int*   src = (const int*)d_in[1];
    const int*   dst = (const int*)d_in[2];
    const float* U   = (const float*)d_in[3];
    const float* V   = (const float*)d_in[4];
    float* out = (float*)d_out;

    // ws layout (ints): deg/cursor [50000] | row_start [50001] |
    //   block_sums [98] | pad | edge_src [1M] | packed [1M] | xh [1.6M ints]
    const size_t deg_off = 0;
    const size_t rs_off  = (size_t)N_NODES;
    const size_t bs_off  = rs_off + N_NODES + 1;
    const size_t es_off  = (bs_off + SCAN_BLOCKS + 3) & ~(size_t)3;
    const size_t pk_off  = es_off + (size_t)N_EDGES;
    const size_t xh_off  = pk_off + (size_t)N_EDGES;
    const size_t mid_bytes  = pk_off * sizeof(int);
    const size_t big_bytes  = xh_off * sizeof(int);
    const size_t huge_bytes = (xh_off + (size_t)N_NODES * D / 2) * sizeof(int);

    const int qb = (N_EDGES / 4 + 255) / 256;  // 4 edges/thread

    if (ws_size >= mid_bytes) {
        int* wsi        = (int*)d_ws;
        int* deg_cur    = wsi + deg_off;
        int* row_start  = wsi + rs_off;
        int* block_sums = wsi + bs_off;
        int* edge_src   = wsi + es_off;
        int* packed     = wsi + pk_off;
        _Float16* xh    = (_Float16*)(wsi + xh_off);

        const bool big  = (ws_size >= big_bytes);
        const bool huge = (ws_size >= huge_bytes);

        hipMemsetAsync(deg_cur, 0, (size_t)N_NODES * sizeof(int), stream);
        if (huge)
            cvt_fp16_kernel<<<N_NODES * D / 4 / 256, 256, 0, stream>>>(x, xh);
        if (big) degree_pack_kernel<<<qb, 256, 0, stream>>>(src, dst, deg_cur, packed);
        else     degree_kernel<<<qb, 256, 0, stream>>>(dst, deg_cur);
        scan_partial_kernel<<<SCAN_BLOCKS, 256, 0, stream>>>(deg_cur, block_sums);
        scan_apply_kernel<<<SCAN_BLOCKS, 256, 0, stream>>>(deg_cur, block_sums, row_start);
        if (big) fill_pos_kernel<<<qb, 256, 0, stream>>>(dst, packed, row_start, edge_src);
        else     fill_kernel<<<qb, 256, 0, stream>>>(src, dst, deg_cur, edge_src);
        if (huge)
            csr_gather_gemm_f16_kernel<<<N_NODES / 8, 512, 0, stream>>>(
                x, xh, row_start, edge_src, U, V, out);
        else
            csr_gather_gemm_kernel<<<N_NODES / 8, 512, 0, stream>>>(
                x, row_start, edge_src, U, V, out);
    } else {
        const size_t agg_bytes = (size_t)N_NODES * D * sizeof(float);
        float* agg = (ws_size >= agg_bytes) ? (float*)d_ws : out;
        hipMemsetAsync(agg, 0, agg_bytes, stream);
        scatter_add_kernel<<<(N_EDGES * 16) / 256, 256, 0, stream>>>(x, src, dst, agg);
        gemm_relu_kernel<<<N_NODES / 16, 256, 0, stream>>>(x, agg, U, V, out);
    }
}